// Round 2
// baseline (1183.085 us; speedup 1.0000x reference)
//
#include <hip/hip_runtime.h>
#include <hip/hip_bf16.h>

// Problem constants
#define BB 4
#define LL 256
#define PP 1024
#define DD 512
#define HH 8
#define HD 64
#define NRBF 50

// ---------------------------------------------------------------------------
// dtype helpers: inputs are fp32 per the reference, but we guard with a
// runtime device-side detector so a bf16 harness policy also works.
// ---------------------------------------------------------------------------
__device__ __forceinline__ float ldf(const void* p, size_t i, bool f32) {
  if (f32) return ((const float*)p)[i];
  return __bfloat162float(((const __hip_bfloat16*)p)[i]);
}

__global__ __launch_bounds__(256) void detect_dtype(const float* q,
                                                    int* flag) {
  __shared__ int cnt;
  if (threadIdx.x == 0) cnt = 0;
  __syncthreads();
  int c = 0;
  for (int i = threadIdx.x; i < 1024; i += 256) {
    unsigned u = __float_as_uint(q[i]);
    unsigned e = (u >> 23) & 0xffu;
    // fp32 N(0,1) values: exponent in [104,140] essentially always.
    if (e >= 104u && e <= 140u) c++;
  }
  atomicAdd(&cnt, c);
  __syncthreads();
  if (threadIdx.x == 0) *flag = (cnt > 512) ? 1 : 0;
}

// ---------------------------------------------------------------------------
// Projection GEMM: Y[M,512] = X[M,512] @ W[512,512] + b (fp32 out to ws)
// 64x64 tile, 4x4 per thread.
// ---------------------------------------------------------------------------
__global__ __launch_bounds__(256) void proj_gemm(
    const void* __restrict__ X, const void* __restrict__ W,
    const void* __restrict__ bias, float* __restrict__ Y,
    const int* __restrict__ flag) {
  __shared__ float As[16][64];
  __shared__ float Bs[16][64];
  const bool f32 = (*flag != 0);
  const int bm = blockIdx.x * 64;
  const int bn = blockIdx.y * 64;
  const int tid = threadIdx.x;
  const int tx = tid & 15;
  const int ty = tid >> 4;
  float acc[4][4] = {};
  for (int k0 = 0; k0 < 512; k0 += 16) {
    if (f32) {
      const float* Xf = (const float*)X;
      const float* Wf = (const float*)W;
      for (int f = tid; f < 64 * 16; f += 256) {
        int r = f >> 4, kk = f & 15;
        As[kk][r] = Xf[(size_t)(bm + r) * 512 + k0 + kk];
      }
      for (int f = tid; f < 16 * 64; f += 256) {
        int kk = f >> 6, c = f & 63;
        Bs[kk][c] = Wf[(size_t)(k0 + kk) * 512 + bn + c];
      }
    } else {
      const __hip_bfloat16* Xb = (const __hip_bfloat16*)X;
      const __hip_bfloat16* Wb = (const __hip_bfloat16*)W;
      for (int f = tid; f < 64 * 16; f += 256) {
        int r = f >> 4, kk = f & 15;
        As[kk][r] = __bfloat162float(Xb[(size_t)(bm + r) * 512 + k0 + kk]);
      }
      for (int f = tid; f < 16 * 64; f += 256) {
        int kk = f >> 6, c = f & 63;
        Bs[kk][c] = __bfloat162float(Wb[(size_t)(k0 + kk) * 512 + bn + c]);
      }
    }
    __syncthreads();
#pragma unroll
    for (int k = 0; k < 16; ++k) {
      float a[4], b[4];
#pragma unroll
      for (int i = 0; i < 4; ++i) a[i] = As[k][ty * 4 + i];
#pragma unroll
      for (int j = 0; j < 4; ++j) b[j] = Bs[k][tx * 4 + j];
#pragma unroll
      for (int i = 0; i < 4; ++i)
#pragma unroll
        for (int j = 0; j < 4; ++j) acc[i][j] = fmaf(a[i], b[j], acc[i][j]);
    }
    __syncthreads();
  }
#pragma unroll
  for (int i = 0; i < 4; ++i) {
    int r = bm + ty * 4 + i;
#pragma unroll
    for (int j = 0; j < 4; ++j) {
      int c = bn + tx * 4 + j;
      Y[(size_t)r * 512 + c] = acc[i][j] + ldf(bias, c, f32);
    }
  }
}

// ---------------------------------------------------------------------------
// Fused attention: one block per (b,l). Scores (QK + rbf bias + mask),
// softmax over P per head, attn_mean output, PV -> AO.
// ---------------------------------------------------------------------------
__global__ __launch_bounds__(256) void attn_kernel(
    const float* __restrict__ Q,   // [B*L, 512] fp32 ws
    const float* __restrict__ K,   // [B*P, 512] fp32 ws
    const float* __restrict__ V,   // [B*P, 512] fp32 ws
    const void* __restrict__ rbf,  // [B,L,P,50]
    const int* __restrict__ mask,  // [B,P]
    const void* __restrict__ Wr,   // [50,8]
    const void* __restrict__ br,   // [8]
    float* __restrict__ AO,        // [B*L, 512] fp32 ws
    void* __restrict__ d_out,      // out1 region at +B*L*D elements
    const int* __restrict__ flag) {
  const int bl = blockIdx.x;  // 0..1023
  const int b = bl >> 8;      // L = 256
  const int tid = threadIdx.x;
  const bool f32 = (*flag != 0);

  __shared__ float qS[512];
  __shared__ float wrS[NRBF * 8];
  __shared__ float brS[8];
  __shared__ float scoresS[HH * PP];  // 32 KB
  __shared__ float rbfS[64 * 52];     // 13.3 KB, stride 52 -> 16B aligned rows

  for (int i = tid; i < 512; i += 256) qS[i] = Q[(size_t)bl * 512 + i];
  for (int i = tid; i < NRBF * 8; i += 256) wrS[i] = ldf(Wr, i, f32);
  if (tid < 8) brS[tid] = ldf(br, tid, f32);
  __syncthreads();

  // ---- score phase: 32 threads per head ----
  const int h = tid >> 5;
  const int lane32 = tid & 31;
  float wr_reg[NRBF];
#pragma unroll
  for (int j = 0; j < NRBF; ++j) wr_reg[j] = wrS[j * 8 + h];
  const float br_h = brS[h];

  for (int t = 0; t < 16; ++t) {
    const int p0 = t * 64;
    const size_t src0 = ((size_t)bl * PP + p0) * NRBF;
    if (f32) {
      const float* rf = (const float*)rbf + src0;
      for (int f = tid; f < 64 * NRBF; f += 256)
        rbfS[(f / NRBF) * 52 + (f % NRBF)] = rf[f];
    } else {
      const __hip_bfloat16* rb = (const __hip_bfloat16*)rbf + src0;
      for (int f = tid; f < 64 * NRBF; f += 256)
        rbfS[(f / NRBF) * 52 + (f % NRBF)] = __bfloat162float(rb[f]);
    }
    __syncthreads();
#pragma unroll
    for (int i = 0; i < 2; ++i) {
      const int pl = lane32 + 32 * i;
      const int p = p0 + pl;
      float biasv = br_h;
      const float* rr = &rbfS[pl * 52];
#pragma unroll
      for (int j = 0; j < NRBF; ++j) biasv = fmaf(rr[j], wr_reg[j], biasv);
      const float* Krow = K + ((size_t)(b * PP + p)) * 512 + h * 64;
      float dot = 0.f;
#pragma unroll
      for (int j = 0; j < 64; j += 4) {
        float4 k4 = *(const float4*)(Krow + j);
        dot = fmaf(qS[h * 64 + j + 0], k4.x, dot);
        dot = fmaf(qS[h * 64 + j + 1], k4.y, dot);
        dot = fmaf(qS[h * 64 + j + 2], k4.z, dot);
        dot = fmaf(qS[h * 64 + j + 3], k4.w, dot);
      }
      float s = dot * 0.125f + biasv;
      if (mask[b * PP + p] == 0) s = -1e9f;
      scoresS[h * PP + p] = s;
    }
    __syncthreads();
  }

  // ---- softmax over P per head; wave w handles heads 2w, 2w+1 ----
  const int wave = tid >> 6;
  const int lane = tid & 63;
  for (int hh = wave * 2; hh < wave * 2 + 2; ++hh) {
    float* sc = &scoresS[hh * PP];
    float m = -3.0e38f;
    for (int i = lane; i < PP; i += 64) m = fmaxf(m, sc[i]);
#pragma unroll
    for (int off = 32; off; off >>= 1) m = fmaxf(m, __shfl_xor(m, off, 64));
    float sum = 0.f;
    for (int i = lane; i < PP; i += 64) {
      float e = __expf(sc[i] - m);
      sc[i] = e;
      sum += e;
    }
#pragma unroll
    for (int off = 32; off; off >>= 1) sum += __shfl_xor(sum, off, 64);
    const float inv = 1.0f / sum;
    for (int i = lane; i < PP; i += 64) sc[i] *= inv;
  }
  __syncthreads();

  // ---- attn_mean over heads -> out1[b,l,p] ----
  {
    float vals[4];
#pragma unroll
    for (int i = 0; i < 4; ++i) {
      const int p = tid + 256 * i;
      float s = 0.f;
#pragma unroll
      for (int hh = 0; hh < HH; ++hh) s += scoresS[hh * PP + p];
      vals[i] = s * 0.125f;
    }
    const size_t base = (size_t)BB * LL * DD + (size_t)bl * PP;
    if (f32) {
      float* o1 = (float*)d_out;
#pragma unroll
      for (int i = 0; i < 4; ++i) o1[base + tid + 256 * i] = vals[i];
    } else {
      __hip_bfloat16* o1 = (__hip_bfloat16*)d_out;
#pragma unroll
      for (int i = 0; i < 4; ++i)
        o1[base + tid + 256 * i] = __float2bfloat16(vals[i]);
    }
  }

  // ---- PV: each thread two consecutive channels ----
  {
    const int c = tid * 2;
    const int hh = c >> 6;
    const float* sc = &scoresS[hh * PP];
    const float2* Vb = (const float2*)(V + (size_t)b * PP * 512 + c);
    float acc0 = 0.f, acc1 = 0.f;
    for (int p = 0; p < PP; ++p) {
      float2 v2 = Vb[(size_t)p * 256];
      float a = sc[p];
      acc0 = fmaf(a, v2.x, acc0);
      acc1 = fmaf(a, v2.y, acc1);
    }
    float* aoRow = AO + (size_t)bl * 512;
    aoRow[c] = acc0;
    aoRow[c + 1] = acc1;
  }
}

// ---------------------------------------------------------------------------
// Output: per-row Wo GEMV + bias + residual + LayerNorm -> out0
// ---------------------------------------------------------------------------
__global__ __launch_bounds__(256) void out_kernel(
    const float* __restrict__ AO, const void* __restrict__ query,
    const void* __restrict__ Wo, const void* __restrict__ bo,
    const void* __restrict__ gamma, const void* __restrict__ beta,
    void* __restrict__ d_out, const int* __restrict__ flag) {
  const int bl = blockIdx.x;
  const int tid = threadIdx.x;
  const bool f32 = (*flag != 0);
  __shared__ float rowS[512];
  __shared__ float xS[512];
  __shared__ float red[16];
  for (int i = tid; i < 512; i += 256) rowS[i] = AO[(size_t)bl * 512 + i];
  __syncthreads();

  float acc0 = 0.f, acc1 = 0.f;
  if (f32) {
    const float* Wf = (const float*)Wo;
    for (int k = 0; k < 512; ++k) {
      const float r = rowS[k];
      acc0 = fmaf(r, Wf[(size_t)k * 512 + tid], acc0);
      acc1 = fmaf(r, Wf[(size_t)k * 512 + tid + 256], acc1);
    }
  } else {
    const __hip_bfloat16* Wb = (const __hip_bfloat16*)Wo;
    for (int k = 0; k < 512; ++k) {
      const float r = rowS[k];
      acc0 = fmaf(r, __bfloat162float(Wb[(size_t)k * 512 + tid]), acc0);
      acc1 = fmaf(r, __bfloat162float(Wb[(size_t)k * 512 + tid + 256]), acc1);
    }
  }
  xS[tid] = acc0 + ldf(bo, tid, f32) + ldf(query, (size_t)bl * 512 + tid, f32);
  xS[tid + 256] = acc1 + ldf(bo, tid + 256, f32) +
                  ldf(query, (size_t)bl * 512 + tid + 256, f32);
  __syncthreads();

  float s = 0.f, s2 = 0.f;
  for (int i = tid; i < 512; i += 256) {
    float v = xS[i];
    s += v;
    s2 += v * v;
  }
#pragma unroll
  for (int off = 32; off; off >>= 1) {
    s += __shfl_xor(s, off, 64);
    s2 += __shfl_xor(s2, off, 64);
  }
  const int wave = tid >> 6;
  const int lane = tid & 63;
  if (lane == 0) {
    red[wave] = s;
    red[8 + wave] = s2;
  }
  __syncthreads();
  if (tid == 0) {
    float ts = 0.f, ts2 = 0.f;
    for (int w = 0; w < 4; ++w) {
      ts += red[w];
      ts2 += red[8 + w];
    }
    red[0] = ts;
    red[1] = ts2;
  }
  __syncthreads();
  const float mu = red[0] * (1.0f / 512.0f);
  const float var = red[1] * (1.0f / 512.0f) - mu * mu;
  const float rstd = rsqrtf(var + 1e-5f);
  if (f32) {
    float* o0 = (float*)d_out;
    for (int i = tid; i < 512; i += 256) {
      float v = (xS[i] - mu) * rstd * ldf(gamma, i, true) + ldf(beta, i, true);
      o0[(size_t)bl * 512 + i] = v;
    }
  } else {
    __hip_bfloat16* o0 = (__hip_bfloat16*)d_out;
    for (int i = tid; i < 512; i += 256) {
      float v =
          (xS[i] - mu) * rstd * ldf(gamma, i, false) + ldf(beta, i, false);
      o0[(size_t)bl * 512 + i] = __float2bfloat16(v);
    }
  }
}

// ---------------------------------------------------------------------------
extern "C" void kernel_launch(void* const* d_in, const int* in_sizes, int n_in,
                              void* d_out, int out_size, void* d_ws,
                              size_t ws_size, hipStream_t stream) {
  const void* query = d_in[0];
  const void* key = d_in[1];
  const void* value = d_in[2];
  const void* rbf = d_in[3];
  const int* key_mask = (const int*)d_in[4];
  const void* Wq = d_in[5];
  const void* bq = d_in[6];
  const void* Wk = d_in[7];
  const void* bk = d_in[8];
  const void* Wv = d_in[9];
  const void* bv = d_in[10];
  const void* Wr = d_in[11];
  const void* br = d_in[12];
  const void* Wo = d_in[13];
  const void* bo = d_in[14];
  const void* gamma = d_in[15];
  const void* beta = d_in[16];

  // ws layout (fp32): Q | K | V | AO | flag  => ~20 MB
  float* ws = (float*)d_ws;
  float* Qw = ws;                         // 524288
  float* Kw = Qw + (size_t)BB * LL * DD;  // 2097152
  float* Vw = Kw + (size_t)BB * PP * DD;  // 2097152
  float* AO = Vw + (size_t)BB * PP * DD;  // 524288
  int* flag = (int*)(AO + (size_t)BB * LL * DD);

  detect_dtype<<<1, 256, 0, stream>>>((const float*)query, flag);
  proj_gemm<<<dim3(16, 8), 256, 0, stream>>>(query, Wq, bq, Qw, flag);
  proj_gemm<<<dim3(64, 8), 256, 0, stream>>>(key, Wk, bk, Kw, flag);
  proj_gemm<<<dim3(64, 8), 256, 0, stream>>>(value, Wv, bv, Vw, flag);
  attn_kernel<<<dim3(BB * LL), 256, 0, stream>>>(Qw, Kw, Vw, rbf, key_mask,
                                                 Wr, br, AO, d_out, flag);
  out_kernel<<<dim3(BB * LL), 256, 0, stream>>>(AO, query, Wo, bo, gamma,
                                                beta, d_out, flag);
}

// Round 3
// 898.016 us; speedup vs baseline: 1.3174x; 1.3174x over previous
//
#include <hip/hip_runtime.h>
#include <hip/hip_bf16.h>

#define BB 4
#define LL 256
#define PP 1024
#define DD 512
#define HH 8
#define HD 64
#define NRBF 50

// ---------------------------------------------------------------------------
// dtype helpers (inputs are fp32 per reference; bf16 fallback kept for safety)
// ---------------------------------------------------------------------------
__device__ __forceinline__ float ldf(const void* p, size_t i, bool f32) {
  if (f32) return ((const float*)p)[i];
  return __bfloat162float(((const __hip_bfloat16*)p)[i]);
}

__global__ __launch_bounds__(256) void detect_dtype(const float* q, int* flag) {
  __shared__ int cnt;
  if (threadIdx.x == 0) cnt = 0;
  __syncthreads();
  int c = 0;
  for (int i = threadIdx.x; i < 1024; i += 256) {
    unsigned u = __float_as_uint(q[i]);
    unsigned e = (u >> 23) & 0xffu;
    if (e >= 104u && e <= 140u) c++;
  }
  atomicAdd(&cnt, c);
  __syncthreads();
  if (threadIdx.x == 0) *flag = (cnt > 512) ? 1 : 0;
}

// ---------------------------------------------------------------------------
// rbf bias: biasW[b,l,h,p] = rbf[b,l,p,:] @ Wr[:,h] + br[h].  Memory-bound.
// ---------------------------------------------------------------------------
__global__ __launch_bounds__(256) void rbf_bias_kernel(
    const void* __restrict__ rbf, const void* __restrict__ Wr,
    const void* __restrict__ br, float* __restrict__ biasW,
    const int* __restrict__ flag) {
  const bool f32 = (*flag != 0);
  __shared__ float wrS[NRBF * 8];
  __shared__ float brS[8];
  const int tid = threadIdx.x;
  for (int i = tid; i < NRBF * 8; i += 256) wrS[i] = ldf(Wr, i, f32);
  if (tid < 8) brS[tid] = ldf(br, tid, f32);
  __syncthreads();
  const size_t row = (size_t)blockIdx.x * 256 + tid;  // (b*L+l)*P + p
  float acc[8];
#pragma unroll
  for (int h = 0; h < 8; ++h) acc[h] = brS[h];
  if (f32) {
    const float2* rp = (const float2*)((const float*)rbf + row * NRBF);
#pragma unroll
    for (int j = 0; j < 25; ++j) {
      float2 r2 = rp[j];
      float4 wa = *(const float4*)&wrS[(2 * j) * 8];
      float4 wb = *(const float4*)&wrS[(2 * j) * 8 + 4];
      float4 wc = *(const float4*)&wrS[(2 * j + 1) * 8];
      float4 wd = *(const float4*)&wrS[(2 * j + 1) * 8 + 4];
      acc[0] = fmaf(r2.x, wa.x, acc[0]); acc[1] = fmaf(r2.x, wa.y, acc[1]);
      acc[2] = fmaf(r2.x, wa.z, acc[2]); acc[3] = fmaf(r2.x, wa.w, acc[3]);
      acc[4] = fmaf(r2.x, wb.x, acc[4]); acc[5] = fmaf(r2.x, wb.y, acc[5]);
      acc[6] = fmaf(r2.x, wb.z, acc[6]); acc[7] = fmaf(r2.x, wb.w, acc[7]);
      acc[0] = fmaf(r2.y, wc.x, acc[0]); acc[1] = fmaf(r2.y, wc.y, acc[1]);
      acc[2] = fmaf(r2.y, wc.z, acc[2]); acc[3] = fmaf(r2.y, wc.w, acc[3]);
      acc[4] = fmaf(r2.y, wd.x, acc[4]); acc[5] = fmaf(r2.y, wd.y, acc[5]);
      acc[6] = fmaf(r2.y, wd.z, acc[6]); acc[7] = fmaf(r2.y, wd.w, acc[7]);
    }
  } else {
    const __hip_bfloat16* rb = (const __hip_bfloat16*)rbf + row * NRBF;
#pragma unroll
    for (int j = 0; j < NRBF; ++j) {
      float r = __bfloat162float(rb[j]);
#pragma unroll
      for (int h = 0; h < 8; ++h) acc[h] = fmaf(r, wrS[j * 8 + h], acc[h]);
    }
  }
  const size_t bl = row >> 10;
  const int p = (int)(row & 1023);
#pragma unroll
  for (int h = 0; h < 8; ++h) biasW[(bl * 8 + h) * 1024 + p] = acc[h];
}

// ---------------------------------------------------------------------------
// Input projection: Y[M,512] = X[M,512]@W[512,512] + b  (fp32 out to ws)
// ---------------------------------------------------------------------------
__global__ __launch_bounds__(256) void proj_in(
    const void* __restrict__ X, const void* __restrict__ W,
    const void* __restrict__ bias, float* __restrict__ Y,
    const int* __restrict__ flag) {
  __shared__ float As[16][64];  // [k][m]
  __shared__ float Bs[16][64];  // [k][n]
  const bool f32 = (*flag != 0);
  const int bm = blockIdx.x * 64, bn = blockIdx.y * 64;
  const int tid = threadIdx.x;
  const int tx = tid & 15, ty = tid >> 4;
  float acc[4][4] = {};
  for (int k0 = 0; k0 < 512; k0 += 16) {
    if (f32) {
      const float* Xf = (const float*)X;
      const float* Wf = (const float*)W;
      {
        int r = tid >> 2, kf = (tid & 3) * 4;
        float4 x4 = *(const float4*)(Xf + (size_t)(bm + r) * 512 + k0 + kf);
        As[kf + 0][r] = x4.x; As[kf + 1][r] = x4.y;
        As[kf + 2][r] = x4.z; As[kf + 3][r] = x4.w;
      }
      {
        int kk = tid >> 4, cf = (tid & 15) * 4;
        *(float4*)&Bs[kk][cf] =
            *(const float4*)(Wf + (size_t)(k0 + kk) * 512 + bn + cf);
      }
    } else {
      const __hip_bfloat16* Xb = (const __hip_bfloat16*)X;
      const __hip_bfloat16* Wb = (const __hip_bfloat16*)W;
      for (int f = tid; f < 64 * 16; f += 256) {
        int r = f >> 4, kk = f & 15;
        As[kk][r] = __bfloat162float(Xb[(size_t)(bm + r) * 512 + k0 + kk]);
      }
      for (int f = tid; f < 16 * 64; f += 256) {
        int kk = f >> 6, c = f & 63;
        Bs[kk][c] = __bfloat162float(Wb[(size_t)(k0 + kk) * 512 + bn + c]);
      }
    }
    __syncthreads();
#pragma unroll
    for (int k = 0; k < 16; ++k) {
      float4 a4 = *(const float4*)&As[k][ty * 4];
      float4 b4 = *(const float4*)&Bs[k][tx * 4];
      acc[0][0] = fmaf(a4.x, b4.x, acc[0][0]); acc[0][1] = fmaf(a4.x, b4.y, acc[0][1]);
      acc[0][2] = fmaf(a4.x, b4.z, acc[0][2]); acc[0][3] = fmaf(a4.x, b4.w, acc[0][3]);
      acc[1][0] = fmaf(a4.y, b4.x, acc[1][0]); acc[1][1] = fmaf(a4.y, b4.y, acc[1][1]);
      acc[1][2] = fmaf(a4.y, b4.z, acc[1][2]); acc[1][3] = fmaf(a4.y, b4.w, acc[1][3]);
      acc[2][0] = fmaf(a4.z, b4.x, acc[2][0]); acc[2][1] = fmaf(a4.z, b4.y, acc[2][1]);
      acc[2][2] = fmaf(a4.z, b4.z, acc[2][2]); acc[2][3] = fmaf(a4.z, b4.w, acc[2][3]);
      acc[3][0] = fmaf(a4.w, b4.x, acc[3][0]); acc[3][1] = fmaf(a4.w, b4.y, acc[3][1]);
      acc[3][2] = fmaf(a4.w, b4.z, acc[3][2]); acc[3][3] = fmaf(a4.w, b4.w, acc[3][3]);
    }
    __syncthreads();
  }
#pragma unroll
  for (int i = 0; i < 4; ++i) {
    int r = bm + ty * 4 + i;
    float4 o;
    o.x = acc[i][0] + ldf(bias, bn + tx * 4 + 0, f32);
    o.y = acc[i][1] + ldf(bias, bn + tx * 4 + 1, f32);
    o.z = acc[i][2] + ldf(bias, bn + tx * 4 + 2, f32);
    o.w = acc[i][3] + ldf(bias, bn + tx * 4 + 3, f32);
    *(float4*)(Y + (size_t)r * 512 + bn + tx * 4) = o;
  }
}

// ---------------------------------------------------------------------------
// Output projection + residual: Xout = AO@Wo + bo + query   (fp32 ws)
// ---------------------------------------------------------------------------
__global__ __launch_bounds__(256) void proj_out(
    const float* __restrict__ X, const void* __restrict__ W,
    const void* __restrict__ bias, const void* __restrict__ resid,
    float* __restrict__ Y, const int* __restrict__ flag) {
  __shared__ float As[16][64];
  __shared__ float Bs[16][64];
  const bool f32 = (*flag != 0);
  const int bm = blockIdx.x * 64, bn = blockIdx.y * 64;
  const int tid = threadIdx.x;
  const int tx = tid & 15, ty = tid >> 4;
  float acc[4][4] = {};
  for (int k0 = 0; k0 < 512; k0 += 16) {
    {
      int r = tid >> 2, kf = (tid & 3) * 4;
      float4 x4 = *(const float4*)(X + (size_t)(bm + r) * 512 + k0 + kf);
      As[kf + 0][r] = x4.x; As[kf + 1][r] = x4.y;
      As[kf + 2][r] = x4.z; As[kf + 3][r] = x4.w;
    }
    if (f32) {
      int kk = tid >> 4, cf = (tid & 15) * 4;
      *(float4*)&Bs[kk][cf] =
          *(const float4*)((const float*)W + (size_t)(k0 + kk) * 512 + bn + cf);
    } else {
      const __hip_bfloat16* Wb = (const __hip_bfloat16*)W;
      for (int f = tid; f < 16 * 64; f += 256) {
        int kk = f >> 6, c = f & 63;
        Bs[kk][c] = __bfloat162float(Wb[(size_t)(k0 + kk) * 512 + bn + c]);
      }
    }
    __syncthreads();
#pragma unroll
    for (int k = 0; k < 16; ++k) {
      float4 a4 = *(const float4*)&As[k][ty * 4];
      float4 b4 = *(const float4*)&Bs[k][tx * 4];
      acc[0][0] = fmaf(a4.x, b4.x, acc[0][0]); acc[0][1] = fmaf(a4.x, b4.y, acc[0][1]);
      acc[0][2] = fmaf(a4.x, b4.z, acc[0][2]); acc[0][3] = fmaf(a4.x, b4.w, acc[0][3]);
      acc[1][0] = fmaf(a4.y, b4.x, acc[1][0]); acc[1][1] = fmaf(a4.y, b4.y, acc[1][1]);
      acc[1][2] = fmaf(a4.y, b4.z, acc[1][2]); acc[1][3] = fmaf(a4.y, b4.w, acc[1][3]);
      acc[2][0] = fmaf(a4.z, b4.x, acc[2][0]); acc[2][1] = fmaf(a4.z, b4.y, acc[2][1]);
      acc[2][2] = fmaf(a4.z, b4.z, acc[2][2]); acc[2][3] = fmaf(a4.z, b4.w, acc[2][3]);
      acc[3][0] = fmaf(a4.w, b4.x, acc[3][0]); acc[3][1] = fmaf(a4.w, b4.y, acc[3][1]);
      acc[3][2] = fmaf(a4.w, b4.z, acc[3][2]); acc[3][3] = fmaf(a4.w, b4.w, acc[3][3]);
    }
    __syncthreads();
  }
#pragma unroll
  for (int i = 0; i < 4; ++i) {
    int r = bm + ty * 4 + i;
    float4 o;
#pragma unroll
    for (int j = 0; j < 4; ++j) {
      int c = bn + tx * 4 + j;
      float v = acc[i][j] + ldf(bias, c, f32) +
                ldf(resid, (size_t)r * 512 + c, f32);
      ((float*)&o)[j] = v;
    }
    *(float4*)(Y + (size_t)r * 512 + bn + tx * 4) = o;
  }
}

// ---------------------------------------------------------------------------
// Attention (big path): bias precomputed. One block per (b,l) via XCD swizzle.
// ---------------------------------------------------------------------------
__global__ __launch_bounds__(256) void attn_big(
    const float* __restrict__ Q, const float* __restrict__ K,
    const float* __restrict__ V, const float* __restrict__ biasW,
    const int* __restrict__ mask, float* __restrict__ AO,
    void* __restrict__ d_out, const int* __restrict__ flag) {
  // XCD swizzle: blocks on XCD pair (2x) handle one batch b -> K/V near-L2.
  const int xcd = blockIdx.x & 7;
  const int idx = blockIdx.x >> 3;  // 0..127
  const int b = xcd >> 1;
  const int l = ((xcd & 1) << 7) | idx;
  const int bl = b * LL + l;
  const int tid = threadIdx.x;
  const bool f32 = (*flag != 0);

  __shared__ float qS[512];
  __shared__ float scoresS[HH * PP];  // 32 KB

  for (int i = tid; i < 512; i += 256) qS[i] = Q[(size_t)bl * 512 + i];
  __syncthreads();

  const int h = tid >> 5, lane32 = tid & 31;
  const float* Kh = K + (size_t)b * PP * 512 + h * 64;
  const float* bh = biasW + ((size_t)bl * 8 + h) * 1024;
  const int* mk = mask + b * PP;

  // ---- scores: two passes of 16 p each; q chunked in registers ----
#pragma unroll
  for (int pass = 0; pass < 2; ++pass) {
    const int pbase = lane32 + pass * 512;  // p = pbase + 32*i
    float acc[16];
#pragma unroll
    for (int i = 0; i < 16; ++i) acc[i] = 0.f;
#pragma unroll
    for (int kc = 0; kc < 4; ++kc) {
      float4 q0 = *(const float4*)&qS[h * 64 + kc * 16 + 0];
      float4 q1 = *(const float4*)&qS[h * 64 + kc * 16 + 4];
      float4 q2 = *(const float4*)&qS[h * 64 + kc * 16 + 8];
      float4 q3 = *(const float4*)&qS[h * 64 + kc * 16 + 12];
#pragma unroll
      for (int i = 0; i < 16; ++i) {
        const float* kr = Kh + (size_t)(pbase + 32 * i) * 512 + kc * 16;
        float4 k0 = *(const float4*)(kr + 0);
        float4 k1 = *(const float4*)(kr + 4);
        float4 k2 = *(const float4*)(kr + 8);
        float4 k3 = *(const float4*)(kr + 12);
        float d0 = fmaf(q0.x, k0.x, fmaf(q0.y, k0.y, fmaf(q0.z, k0.z, q0.w * k0.w)));
        float d1 = fmaf(q1.x, k1.x, fmaf(q1.y, k1.y, fmaf(q1.z, k1.z, q1.w * k1.w)));
        float d2 = fmaf(q2.x, k2.x, fmaf(q2.y, k2.y, fmaf(q2.z, k2.z, q2.w * k2.w)));
        float d3 = fmaf(q3.x, k3.x, fmaf(q3.y, k3.y, fmaf(q3.z, k3.z, q3.w * k3.w)));
        acc[i] += (d0 + d1) + (d2 + d3);
      }
    }
#pragma unroll
    for (int i = 0; i < 16; ++i) {
      const int p = pbase + 32 * i;
      float s = acc[i] * 0.125f + bh[p];
      if (mk[p] == 0) s = -1e9f;
      scoresS[h * 1024 + p] = s;
    }
  }
  __syncthreads();

  // ---- softmax per head; wave w handles heads 2w,2w+1 ----
  const int wave = tid >> 6, lane = tid & 63;
  for (int hh = wave * 2; hh < wave * 2 + 2; ++hh) {
    float* sc = &scoresS[hh * 1024];
    float m = -3.0e38f;
    for (int i = lane; i < PP; i += 64) m = fmaxf(m, sc[i]);
#pragma unroll
    for (int off = 32; off; off >>= 1) m = fmaxf(m, __shfl_xor(m, off, 64));
    float sum = 0.f;
    for (int i = lane; i < PP; i += 64) {
      float e = __expf(sc[i] - m);
      sc[i] = e;
      sum += e;
    }
#pragma unroll
    for (int off = 32; off; off >>= 1) sum += __shfl_xor(sum, off, 64);
    const float inv = 1.0f / sum;
    for (int i = lane; i < PP; i += 64) sc[i] *= inv;
  }
  __syncthreads();

  // ---- attn_mean: thread owns 4 consecutive p ----
  {
    float4 s = {0.f, 0.f, 0.f, 0.f};
#pragma unroll
    for (int hh = 0; hh < HH; ++hh) {
      float4 v = *(const float4*)&scoresS[hh * 1024 + tid * 4];
      s.x += v.x; s.y += v.y; s.z += v.z; s.w += v.w;
    }
    s.x *= 0.125f; s.y *= 0.125f; s.z *= 0.125f; s.w *= 0.125f;
    const size_t base = (size_t)BB * LL * DD + (size_t)bl * PP + tid * 4;
    if (f32) {
      *(float4*)((float*)d_out + base) = s;
    } else {
      __hip_bfloat16* o1 = (__hip_bfloat16*)d_out;
      o1[base + 0] = __float2bfloat16(s.x);
      o1[base + 1] = __float2bfloat16(s.y);
      o1[base + 2] = __float2bfloat16(s.z);
      o1[base + 3] = __float2bfloat16(s.w);
    }
  }

  // ---- PV: thread owns channels (c, c+1); 4-p unroll, 2 partial pairs ----
  {
    const int c = tid * 2;
    const float* sc = &scoresS[(c >> 6) * 1024];
    const float2* Vb = (const float2*)(V + (size_t)b * PP * 512 + c);
    float a0 = 0.f, a1 = 0.f, b0 = 0.f, b1 = 0.f;
    for (int p4 = 0; p4 < PP; p4 += 4) {
      float4 s4 = *(const float4*)(sc + p4);
      float2 v0 = Vb[(size_t)(p4 + 0) * 256];
      float2 v1 = Vb[(size_t)(p4 + 1) * 256];
      float2 v2 = Vb[(size_t)(p4 + 2) * 256];
      float2 v3 = Vb[(size_t)(p4 + 3) * 256];
      a0 = fmaf(s4.x, v0.x, a0); a1 = fmaf(s4.x, v0.y, a1);
      b0 = fmaf(s4.y, v1.x, b0); b1 = fmaf(s4.y, v1.y, b1);
      a0 = fmaf(s4.z, v2.x, a0); a1 = fmaf(s4.z, v2.y, a1);
      b0 = fmaf(s4.w, v3.x, b0); b1 = fmaf(s4.w, v3.y, b1);
    }
    float* aoRow = AO + (size_t)bl * 512;
    aoRow[c] = a0 + b0;
    aoRow[c + 1] = a1 + b1;
  }
}

// ---------------------------------------------------------------------------
// LayerNorm rows of Xw -> out0
// ---------------------------------------------------------------------------
__global__ __launch_bounds__(256) void ln_kernel(
    const float* __restrict__ Xw, const void* __restrict__ gamma,
    const void* __restrict__ beta, void* __restrict__ d_out,
    const int* __restrict__ flag) {
  const int bl = blockIdx.x;
  const int tid = threadIdx.x;
  const bool f32 = (*flag != 0);
  __shared__ float red[16];
  float v0 = Xw[(size_t)bl * 512 + tid];
  float v1 = Xw[(size_t)bl * 512 + tid + 256];
  float s = v0 + v1, s2 = v0 * v0 + v1 * v1;
#pragma unroll
  for (int off = 32; off; off >>= 1) {
    s += __shfl_xor(s, off, 64);
    s2 += __shfl_xor(s2, off, 64);
  }
  const int wave = tid >> 6, lane = tid & 63;
  if (lane == 0) { red[wave] = s; red[8 + wave] = s2; }
  __syncthreads();
  if (tid == 0) {
    float ts = 0.f, ts2 = 0.f;
    for (int w = 0; w < 4; ++w) { ts += red[w]; ts2 += red[8 + w]; }
    red[0] = ts; red[1] = ts2;
  }
  __syncthreads();
  const float mu = red[0] * (1.0f / 512.0f);
  const float var = red[1] * (1.0f / 512.0f) - mu * mu;
  const float rstd = rsqrtf(var + 1e-5f);
  float o0 = (v0 - mu) * rstd * ldf(gamma, tid, f32) + ldf(beta, tid, f32);
  float o1 = (v1 - mu) * rstd * ldf(gamma, tid + 256, f32) +
             ldf(beta, tid + 256, f32);
  if (f32) {
    float* o = (float*)d_out;
    o[(size_t)bl * 512 + tid] = o0;
    o[(size_t)bl * 512 + tid + 256] = o1;
  } else {
    __hip_bfloat16* o = (__hip_bfloat16*)d_out;
    o[(size_t)bl * 512 + tid] = __float2bfloat16(o0);
    o[(size_t)bl * 512 + tid + 256] = __float2bfloat16(o1);
  }
}

// ---------------------------------------------------------------------------
// Fallback path (small ws): round-2 proven kernels
// ---------------------------------------------------------------------------
__global__ __launch_bounds__(256) void attn_small(
    const float* __restrict__ Q, const float* __restrict__ K,
    const float* __restrict__ V, const void* __restrict__ rbf,
    const int* __restrict__ mask, const void* __restrict__ Wr,
    const void* __restrict__ br, float* __restrict__ AO,
    void* __restrict__ d_out, const int* __restrict__ flag) {
  const int bl = blockIdx.x;
  const int b = bl >> 8;
  const int tid = threadIdx.x;
  const bool f32 = (*flag != 0);
  __shared__ float qS[512];
  __shared__ float wrS[NRBF * 8];
  __shared__ float brS[8];
  __shared__ float scoresS[HH * PP];
  __shared__ float rbfS[64 * 52];
  for (int i = tid; i < 512; i += 256) qS[i] = Q[(size_t)bl * 512 + i];
  for (int i = tid; i < NRBF * 8; i += 256) wrS[i] = ldf(Wr, i, f32);
  if (tid < 8) brS[tid] = ldf(br, tid, f32);
  __syncthreads();
  const int h = tid >> 5;
  const int lane32 = tid & 31;
  float wr_reg[NRBF];
#pragma unroll
  for (int j = 0; j < NRBF; ++j) wr_reg[j] = wrS[j * 8 + h];
  const float br_h = brS[h];
  for (int t = 0; t < 16; ++t) {
    const int p0 = t * 64;
    const size_t src0 = ((size_t)bl * PP + p0) * NRBF;
    if (f32) {
      const float* rf = (const float*)rbf + src0;
      for (int f = tid; f < 64 * NRBF; f += 256)
        rbfS[(f / NRBF) * 52 + (f % NRBF)] = rf[f];
    } else {
      const __hip_bfloat16* rb = (const __hip_bfloat16*)rbf + src0;
      for (int f = tid; f < 64 * NRBF; f += 256)
        rbfS[(f / NRBF) * 52 + (f % NRBF)] = __bfloat162float(rb[f]);
    }
    __syncthreads();
#pragma unroll
    for (int i = 0; i < 2; ++i) {
      const int pl = lane32 + 32 * i;
      const int p = p0 + pl;
      float biasv = br_h;
      const float* rr = &rbfS[pl * 52];
#pragma unroll
      for (int j = 0; j < NRBF; ++j) biasv = fmaf(rr[j], wr_reg[j], biasv);
      const float* Krow = K + ((size_t)(b * PP + p)) * 512 + h * 64;
      float dot = 0.f;
#pragma unroll
      for (int j = 0; j < 64; j += 4) {
        float4 k4 = *(const float4*)(Krow + j);
        dot = fmaf(qS[h * 64 + j + 0], k4.x, dot);
        dot = fmaf(qS[h * 64 + j + 1], k4.y, dot);
        dot = fmaf(qS[h * 64 + j + 2], k4.z, dot);
        dot = fmaf(qS[h * 64 + j + 3], k4.w, dot);
      }
      float s = dot * 0.125f + biasv;
      if (mask[b * PP + p] == 0) s = -1e9f;
      scoresS[h * PP + p] = s;
    }
    __syncthreads();
  }
  const int wave = tid >> 6, lane = tid & 63;
  for (int hh = wave * 2; hh < wave * 2 + 2; ++hh) {
    float* sc = &scoresS[hh * PP];
    float m = -3.0e38f;
    for (int i = lane; i < PP; i += 64) m = fmaxf(m, sc[i]);
#pragma unroll
    for (int off = 32; off; off >>= 1) m = fmaxf(m, __shfl_xor(m, off, 64));
    float sum = 0.f;
    for (int i = lane; i < PP; i += 64) {
      float e = __expf(sc[i] - m);
      sc[i] = e;
      sum += e;
    }
#pragma unroll
    for (int off = 32; off; off >>= 1) sum += __shfl_xor(sum, off, 64);
    const float inv = 1.0f / sum;
    for (int i = lane; i < PP; i += 64) sc[i] *= inv;
  }
  __syncthreads();
  {
    float vals[4];
#pragma unroll
    for (int i = 0; i < 4; ++i) {
      const int p = tid + 256 * i;
      float s = 0.f;
#pragma unroll
      for (int hh = 0; hh < HH; ++hh) s += scoresS[hh * PP + p];
      vals[i] = s * 0.125f;
    }
    const size_t base = (size_t)BB * LL * DD + (size_t)bl * PP;
    if (f32) {
      float* o1 = (float*)d_out;
#pragma unroll
      for (int i = 0; i < 4; ++i) o1[base + tid + 256 * i] = vals[i];
    } else {
      __hip_bfloat16* o1 = (__hip_bfloat16*)d_out;
#pragma unroll
      for (int i = 0; i < 4; ++i)
        o1[base + tid + 256 * i] = __float2bfloat16(vals[i]);
    }
  }
  {
    const int c = tid * 2;
    const float* sc = &scoresS[(c >> 6) * PP];
    const float2* Vb = (const float2*)(V + (size_t)b * PP * 512 + c);
    float acc0 = 0.f, acc1 = 0.f;
    for (int p = 0; p < PP; ++p) {
      float2 v2 = Vb[(size_t)p * 256];
      float a = sc[p];
      acc0 = fmaf(a, v2.x, acc0);
      acc1 = fmaf(a, v2.y, acc1);
    }
    float* aoRow = AO + (size_t)bl * 512;
    aoRow[c] = acc0;
    aoRow[c + 1] = acc1;
  }
}

__global__ __launch_bounds__(256) void out_small(
    const float* __restrict__ AO, const void* __restrict__ query,
    const void* __restrict__ Wo, const void* __restrict__ bo,
    const void* __restrict__ gamma, const void* __restrict__ beta,
    void* __restrict__ d_out, const int* __restrict__ flag) {
  const int bl = blockIdx.x;
  const int tid = threadIdx.x;
  const bool f32 = (*flag != 0);
  __shared__ float rowS[512];
  __shared__ float xS[512];
  __shared__ float red[16];
  for (int i = tid; i < 512; i += 256) rowS[i] = AO[(size_t)bl * 512 + i];
  __syncthreads();
  float acc0 = 0.f, acc1 = 0.f;
  if (f32) {
    const float* Wf = (const float*)Wo;
    for (int k = 0; k < 512; ++k) {
      const float r = rowS[k];
      acc0 = fmaf(r, Wf[(size_t)k * 512 + tid], acc0);
      acc1 = fmaf(r, Wf[(size_t)k * 512 + tid + 256], acc1);
    }
  } else {
    const __hip_bfloat16* Wb = (const __hip_bfloat16*)Wo;
    for (int k = 0; k < 512; ++k) {
      const float r = rowS[k];
      acc0 = fmaf(r, __bfloat162float(Wb[(size_t)k * 512 + tid]), acc0);
      acc1 = fmaf(r, __bfloat162float(Wb[(size_t)k * 512 + tid + 256]), acc1);
    }
  }
  xS[tid] = acc0 + ldf(bo, tid, f32) + ldf(query, (size_t)bl * 512 + tid, f32);
  xS[tid + 256] = acc1 + ldf(bo, tid + 256, f32) +
                  ldf(query, (size_t)bl * 512 + tid + 256, f32);
  __syncthreads();
  float s = 0.f, s2 = 0.f;
  for (int i = tid; i < 512; i += 256) {
    float v = xS[i];
    s += v;
    s2 += v * v;
  }
#pragma unroll
  for (int off = 32; off; off >>= 1) {
    s += __shfl_xor(s, off, 64);
    s2 += __shfl_xor(s2, off, 64);
  }
  const int wave = tid >> 6, lane = tid & 63;
  if (lane == 0) { red[wave] = s; red[8 + wave] = s2; }
  __syncthreads();
  if (tid == 0) {
    float ts = 0.f, ts2 = 0.f;
    for (int w = 0; w < 4; ++w) { ts += red[w]; ts2 += red[8 + w]; }
    red[0] = ts; red[1] = ts2;
  }
  __syncthreads();
  const float mu = red[0] * (1.0f / 512.0f);
  const float var = red[1] * (1.0f / 512.0f) - mu * mu;
  const float rstd = rsqrtf(var + 1e-5f);
  if (f32) {
    float* o0 = (float*)d_out;
    for (int i = tid; i < 512; i += 256) {
      float v = (xS[i] - mu) * rstd * ldf(gamma, i, true) + ldf(beta, i, true);
      o0[(size_t)bl * 512 + i] = v;
    }
  } else {
    __hip_bfloat16* o0 = (__hip_bfloat16*)d_out;
    for (int i = tid; i < 512; i += 256) {
      float v =
          (xS[i] - mu) * rstd * ldf(gamma, i, false) + ldf(beta, i, false);
      o0[(size_t)bl * 512 + i] = __float2bfloat16(v);
    }
  }
}

// ---------------------------------------------------------------------------
extern "C" void kernel_launch(void* const* d_in, const int* in_sizes, int n_in,
                              void* d_out, int out_size, void* d_ws,
                              size_t ws_size, hipStream_t stream) {
  const void* query = d_in[0];
  const void* key = d_in[1];
  const void* value = d_in[2];
  const void* rbf = d_in[3];
  const int* key_mask = (const int*)d_in[4];
  const void* Wq = d_in[5];
  const void* bq = d_in[6];
  const void* Wk = d_in[7];
  const void* bk = d_in[8];
  const void* Wv = d_in[9];
  const void* bv = d_in[10];
  const void* Wr = d_in[11];
  const void* br = d_in[12];
  const void* Wo = d_in[13];
  const void* bo = d_in[14];
  const void* gamma = d_in[15];
  const void* beta = d_in[16];

  // ws: [flag 16B] Q | K | V | AO | X | bias
  int* flag = (int*)d_ws;
  float* base = (float*)d_ws + 4;
  float* Qw = base;
  float* Kw = Qw + (size_t)BB * LL * DD;    // +524288
  float* Vw = Kw + (size_t)BB * PP * DD;    // +2097152
  float* AO = Vw + (size_t)BB * PP * DD;    // +2097152
  float* Xw = AO + (size_t)BB * LL * DD;    // +524288
  float* biasW = Xw + (size_t)BB * LL * DD; // +524288
  const size_t need_big =
      16 + sizeof(float) * ((size_t)BB * LL * DD * 3 + (size_t)BB * PP * DD * 2 +
                            (size_t)BB * LL * HH * PP);
  const bool big = ws_size >= need_big;

  detect_dtype<<<1, 256, 0, stream>>>((const float*)query, flag);
  proj_in<<<dim3(16, 8), 256, 0, stream>>>(query, Wq, bq, Qw, flag);
  proj_in<<<dim3(64, 8), 256, 0, stream>>>(key, Wk, bk, Kw, flag);
  proj_in<<<dim3(64, 8), 256, 0, stream>>>(value, Wv, bv, Vw, flag);
  if (big) {
    rbf_bias_kernel<<<dim3(BB * LL * PP / 256), 256, 0, stream>>>(
        rbf, Wr, br, biasW, flag);
    attn_big<<<dim3(BB * LL), 256, 0, stream>>>(Qw, Kw, Vw, biasW, key_mask,
                                                AO, d_out, flag);
    proj_out<<<dim3(16, 8), 256, 0, stream>>>(AO, Wo, bo, query, Xw, flag);
    ln_kernel<<<dim3(BB * LL), 256, 0, stream>>>(Xw, gamma, beta, d_out, flag);
  } else {
    attn_small<<<dim3(BB * LL), 256, 0, stream>>>(Qw, Kw, Vw, rbf, key_mask,
                                                  Wr, br, AO, d_out, flag);
    out_small<<<dim3(BB * LL), 256, 0, stream>>>(AO, query, Wo, bo, gamma,
                                                 beta, d_out, flag);
  }
}